// Round 3
// baseline (773.456 us; speedup 1.0000x reference)
//
#include <hip/hip_runtime.h>
#include <hip/hip_bf16.h>
#include <hip/hip_fp16.h>

// Problem constants
#define TOKENS 4096
#define IN_F   4096
#define OUT_F  11008
#define GROUPS_PER_ROW 256                 // IN_F / 16
#define TOTAL_GROUPS (OUT_F * GROUPS_PER_ROW)

// GEMM tiling (m97 structure: 128x128 tile, BK=32, 4 waves, double-buffered LDS)
#define BM 128
#define BN 128
#define BK 32
#define KT_COUNT (IN_F / BK)               // 128 K-tiles
#define NBM (TOKENS / BM)                  // 32
#define NBN (OUT_F / BN)                   // 86
#define NWG (NBM * NBN)                    // 2752 (divisible by 8 -> simple XCD swizzle)

typedef __bf16 bf16x8 __attribute__((ext_vector_type(8)));
typedef float  f32x4  __attribute__((ext_vector_type(4)));

static __device__ __forceinline__ unsigned short f2bf(float f) {
  // round-to-nearest-even f32 -> bf16 (inputs are finite)
  unsigned int u = __float_as_uint(f);
  u += 0x7fff + ((u >> 16) & 1);
  return (unsigned short)(u >> 16);
}

static __device__ __forceinline__ void load_lds16(const void* g, void* l) {
  // async global->LDS, 16B per lane. LDS dest is wave-uniform base + lane*16.
  __builtin_amdgcn_global_load_lds(
      (const __attribute__((address_space(1))) void*)g,
      (__attribute__((address_space(3))) void*)l, 16, 0, 0);
}

// ---------------------------------------------------------------------------
// Pass 1a: x (f32) -> Xb (bf16) in GEMM-tile-linear layout [mt][kt][128][32]
// ---------------------------------------------------------------------------
__global__ void conv_x(const float* __restrict__ x, unsigned short* __restrict__ Xb) {
  int t  = blockIdx.x * 256 + threadIdx.x;   // one thread per 8 elements
  int m  = t >> 9;                            // IN_F/8 = 512 chunks per row
  int c8 = t & 511;
  int k0 = c8 << 3;

  const float4* p = (const float4*)(x + (size_t)m * IN_F + k0);
  float4 a = p[0];
  float4 b = p[1];

  unsigned int w0 = (unsigned int)f2bf(a.x) | ((unsigned int)f2bf(a.y) << 16);
  unsigned int w1 = (unsigned int)f2bf(a.z) | ((unsigned int)f2bf(a.w) << 16);
  unsigned int w2 = (unsigned int)f2bf(b.x) | ((unsigned int)f2bf(b.y) << 16);
  unsigned int w3 = (unsigned int)f2bf(b.z) | ((unsigned int)f2bf(b.w) << 16);

  int mt = m >> 7, r = m & 127;
  int kt = k0 >> 5, c = k0 & 31;
  size_t base = (((size_t)(mt * KT_COUNT + kt)) * 128 + r) * 32 + c;
  *(uint4*)(Xb + base) = make_uint4(w0, w1, w2, w3);
}

// ---------------------------------------------------------------------------
// Pass 1b: dequantize 4-bit groups -> Wb (bf16) in tile-linear [nt][kt][128][32]
// One thread per group of 16 weights (8 packed int32, 1 norm).
// NOTE: weight_norm is float16 in the reference; the harness only delivers
// bf16/f32/int -> it arrives as float32. Read as float*. (Round-1 failure:
// reading it as __half gave the measured absmax 4.2e4 signature.)
// ref: w = q/15 * 2n - n; even idx = low nibble, odd idx = high nibble.
// ---------------------------------------------------------------------------
__global__ void dequant_w(const int* __restrict__ wq, const float* __restrict__ wn,
                          unsigned short* __restrict__ Wb) {
  int g  = blockIdx.x * 256 + threadIdx.x;   // grid covers TOTAL_GROUPS exactly
  int o  = g >> 8;                            // out feature
  int gi = g & 255;                           // group within row

  const int4* p = (const int4*)(wq + (size_t)g * 8);
  int4 v0 = p[0];
  int4 v1 = p[1];
  float n = wn[g];
  float s = n * (2.0f / 15.0f);

  int q[8] = {v0.x, v0.y, v0.z, v0.w, v1.x, v1.y, v1.z, v1.w};
  unsigned int w32[8];
#pragma unroll
  for (int j = 0; j < 8; ++j) {
    unsigned short lo = f2bf((float)(q[j] & 15) * s - n);
    unsigned short hi = f2bf((float)((q[j] >> 4) & 15) * s - n);
    w32[j] = (unsigned int)lo | ((unsigned int)hi << 16);  // elem 2j low addr
  }

  int k0 = gi << 4;
  int nt = o >> 7, r = o & 127;
  int kt = k0 >> 5, c = k0 & 31;                // c in {0,16}
  size_t base = (((size_t)(nt * KT_COUNT + kt)) * 128 + r) * 32 + c;
  *(uint4*)(Wb + base)     = make_uint4(w32[0], w32[1], w32[2], w32[3]);
  *(uint4*)(Wb + base + 8) = make_uint4(w32[4], w32[5], w32[6], w32[7]);
}

// ---------------------------------------------------------------------------
// Pass 2: bf16 GEMM, C = Xb @ Wb^T + bias  (m97 structure)
// 128x128 tile, BK=32, 256 threads (4 waves, 2x2), each wave 64x64 out,
// mfma_f32_16x16x32_bf16, global_load_lds width=16, LDS double-buffer.
// ---------------------------------------------------------------------------
__global__ __launch_bounds__(256) void gemm_bt(
    const unsigned short* __restrict__ Xb, const unsigned short* __restrict__ Wb,
    const float* __restrict__ bias, float* __restrict__ out) {
  __shared__ __align__(16) unsigned short As[2][BM * BK];   // 8 KB each
  __shared__ __align__(16) unsigned short Bs[2][BN * BK];

  // XCD-aware bijective swizzle (NWG=2752 divisible by 8)
  int bid = blockIdx.x;
  int swz = (bid & 7) * (NWG / 8) + (bid >> 3);
  int bm  = swz / NBN;
  int bn  = swz % NBN;

  int tid  = threadIdx.x;
  int lane = tid & 63;
  int wid  = tid >> 6;
  int wr   = wid >> 1, wc = wid & 1;
  int lr   = lane & 15;            // M/N index within 16
  int lk   = (lane >> 4) << 3;     // K offset (8 contiguous bf16 per lane)

  const char* aTiles = (const char*)Xb + (size_t)bm * KT_COUNT * 8192;
  const char* bTiles = (const char*)Wb + (size_t)bn * KT_COUNT * 8192;
  int soff = wid * 1024 + lane * 16;   // per-lane source offset within a call

#define STAGE(buf_, kt_) do {                                          \
    const char* as_ = aTiles + (size_t)(kt_) * 8192 + soff;            \
    const char* bs_ = bTiles + (size_t)(kt_) * 8192 + soff;            \
    char* ad_ = (char*)&As[buf_][0] + wid * 1024;                      \
    char* bd_ = (char*)&Bs[buf_][0] + wid * 1024;                      \
    load_lds16(as_,        ad_);                                       \
    load_lds16(as_ + 4096, ad_ + 4096);                                \
    load_lds16(bs_,        bd_);                                       \
    load_lds16(bs_ + 4096, bd_ + 4096);                                \
  } while (0)

  f32x4 acc[4][4] = {};

  auto compute = [&](int buf) {
    bf16x8 a[4], b[4];
#pragma unroll
    for (int m = 0; m < 4; ++m)
      a[m] = *(const bf16x8*)&As[buf][(wr * 64 + m * 16 + lr) * BK + lk];
#pragma unroll
    for (int n = 0; n < 4; ++n)
      b[n] = *(const bf16x8*)&Bs[buf][(wc * 64 + n * 16 + lr) * BK + lk];
#pragma unroll
    for (int m = 0; m < 4; ++m)
#pragma unroll
      for (int n = 0; n < 4; ++n)
        acc[m][n] = __builtin_amdgcn_mfma_f32_16x16x32_bf16(a[m], b[n], acc[m][n], 0, 0, 0);
  };

  STAGE(0, 0);
  __syncthreads();
  int cur = 0;
  for (int kt = 0; kt < KT_COUNT - 1; ++kt) {
    STAGE(cur ^ 1, kt + 1);      // async prefetch next K-tile
    compute(cur);                // ds_read + 16 MFMA on current
    __syncthreads();             // drains vmcnt (stage done) + read-done barrier
    cur ^= 1;
  }
  compute(cur);

  // Epilogue: C/D layout col=lane&15, row=(lane>>4)*4+reg  [m89-verified]
  float bv[4];
#pragma unroll
  for (int n = 0; n < 4; ++n)
    bv[n] = bias[bn * 128 + wc * 64 + n * 16 + lr];

  int row0 = bm * 128 + wr * 64 + ((lane >> 4) << 2);
  int col0 = bn * 128 + wc * 64 + lr;
#pragma unroll
  for (int m = 0; m < 4; ++m) {
#pragma unroll
    for (int n = 0; n < 4; ++n) {
#pragma unroll
      for (int r = 0; r < 4; ++r) {
        int row = row0 + m * 16 + r;
        int col = col0 + n * 16;
        out[(size_t)row * OUT_F + col] = acc[m][n][r] + bv[n];
      }
    }
  }
#undef STAGE
}

// ---------------------------------------------------------------------------
extern "C" void kernel_launch(void* const* d_in, const int* in_sizes, int n_in,
                              void* d_out, int out_size, void* d_ws, size_t ws_size,
                              hipStream_t stream) {
  const float*  x    = (const float*)d_in[0];
  const int*    wq   = (const int*)d_in[1];
  const float*  wn   = (const float*)d_in[2];   // fp16 widened to f32 by harness
  const float*  bias = (const float*)d_in[3];
  float*        out  = (float*)d_out;

  // Workspace: Xb (32 MB) then Wb (~86 MB), both bf16 tile-linear.
  unsigned short* Xb = (unsigned short*)d_ws;
  unsigned short* Wb = Xb + (size_t)TOKENS * IN_F;

  conv_x<<<(TOKENS * IN_F / 8) / 256, 256, 0, stream>>>(x, Xb);
  dequant_w<<<TOTAL_GROUPS / 256, 256, 0, stream>>>(wq, wn, Wb);
  gemm_bt<<<NWG, 256, 0, stream>>>(Xb, Wb, bias, out);
}

// Round 4
// 657.768 us; speedup vs baseline: 1.1759x; 1.1759x over previous
//
#include <hip/hip_runtime.h>
#include <hip/hip_bf16.h>

// Problem constants
#define TOKENS 4096
#define IN_F   4096
#define OUT_F  11008
#define GROUPS_PER_ROW 256                 // IN_F / 16
#define TOTAL_GROUPS (OUT_F * GROUPS_PER_ROW)

// 8-phase 256x256 template geometry (m201 structure)
#define BK 64
#define KT 64                              // IN_F / BK
#define NBM 16                             // TOKENS / 256
#define NBN 43                             // OUT_F / 256
#define NWG (NBM * NBN)                    // 688 (divisible by 8)

typedef __bf16 bf16x8 __attribute__((ext_vector_type(8)));
typedef float  f32x4  __attribute__((ext_vector_type(4)));

static __device__ __forceinline__ unsigned short f2bf(float f) {
  unsigned int u = __float_as_uint(f);
  u += 0x7fff + ((u >> 16) & 1);
  return (unsigned short)(u >> 16);
}

static __device__ __forceinline__ void load_lds16(const void* g, void* l) {
  // async global->LDS, 16B/lane. LDS dest = wave-uniform base + lane*16 (linear).
  __builtin_amdgcn_global_load_lds(
      (const __attribute__((address_space(1))) void*)g,
      (__attribute__((address_space(3))) void*)l, 16, 0, 0);
}

// LDS bank swizzle (T2): qs = q ^ ((q>>3)&0x70) within each 16KB half-tile.
// Producers (prep kernels) store chunk q at qs (inverse==same, involution);
// GEMM stages LINEARLY (global_load_lds) and applies the XOR on ds_read.

// ---------------------------------------------------------------------------
// Pass 1a: x (f32) -> Xb bf16, layout [mt(16)][kt(64)][h(2)][swz(128x64)]
// half h holds M rows mt*256+h*128 .. +127, K cols kt*64..+63, row-major 128B/row.
// ---------------------------------------------------------------------------
__global__ void conv_x(const float* __restrict__ x, unsigned short* __restrict__ Xb) {
  int t  = blockIdx.x * 256 + threadIdx.x;   // one thread per 8 K-elements
  int m  = t >> 9;
  int k0 = (t & 511) << 3;

  const float4* p = (const float4*)(x + (size_t)m * IN_F + k0);
  float4 a = p[0];
  float4 b = p[1];

  unsigned int w0 = (unsigned int)f2bf(a.x) | ((unsigned int)f2bf(a.y) << 16);
  unsigned int w1 = (unsigned int)f2bf(a.z) | ((unsigned int)f2bf(a.w) << 16);
  unsigned int w2 = (unsigned int)f2bf(b.x) | ((unsigned int)f2bf(b.y) << 16);
  unsigned int w3 = (unsigned int)f2bf(b.z) | ((unsigned int)f2bf(b.w) << 16);

  int mt = m >> 8, h = (m >> 7) & 1, r = m & 127;
  int kt = k0 >> 6;
  int q  = r * 128 + (k0 & 63) * 2;          // byte offset in half-tile
  int qs = q ^ ((q >> 3) & 0x70);            // pre-swizzle
  char* dst = (char*)Xb + ((((size_t)mt * KT + kt) * 2 + h) * 16384) + qs;
  *(uint4*)dst = make_uint4(w0, w1, w2, w3);
}

// ---------------------------------------------------------------------------
// Pass 1b: dequant 4-bit -> Wb bf16, layout [nt(43)][kt(64)][h(2)][swz(128x64)]
// weight_norm is fp16 in the reference -> harness widens to f32 (round-1 lesson).
// ---------------------------------------------------------------------------
__global__ void dequant_w(const int* __restrict__ wq, const float* __restrict__ wn,
                          unsigned short* __restrict__ Wb) {
  int g  = blockIdx.x * 256 + threadIdx.x;   // one thread per group of 16
  int o  = g >> 8;                            // out feature
  int gi = g & 255;                           // group within row (K block of 16)

  const int4* p = (const int4*)(wq + (size_t)g * 8);
  int4 v0 = p[0];
  int4 v1 = p[1];
  float n = wn[g];
  float s = n * (2.0f / 15.0f);

  int q8[8] = {v0.x, v0.y, v0.z, v0.w, v1.x, v1.y, v1.z, v1.w};
  unsigned int w32[8];
#pragma unroll
  for (int j = 0; j < 8; ++j) {
    unsigned short lo = f2bf((float)(q8[j] & 15) * s - n);
    unsigned short hi = f2bf((float)((q8[j] >> 4) & 15) * s - n);
    w32[j] = (unsigned int)lo | ((unsigned int)hi << 16);  // elem 2j at low addr
  }

  int nt = o >> 8, h = (o >> 7) & 1, r = o & 127;
  int kt = gi >> 2;
  int cb = (gi & 3) * 32;                    // byte col within 128B row
  int q0 = r * 128 + cb;
  int q1 = q0 + 16;
  int qs0 = q0 ^ ((q0 >> 3) & 0x70);
  int qs1 = q1 ^ ((q1 >> 3) & 0x70);
  char* base = (char*)Wb + ((((size_t)nt * KT + kt) * 2 + h) * 16384);
  *(uint4*)(base + qs0) = make_uint4(w32[0], w32[1], w32[2], w32[3]);
  *(uint4*)(base + qs1) = make_uint4(w32[4], w32[5], w32[6], w32[7]);
}

// ---------------------------------------------------------------------------
// Pass 2: 256x256 8-phase bf16 GEMM (T2+T3+T4+T5), C = Xb @ Wb^T + bias.
// 512 threads = 8 waves (2M x 4N); per-wave out 128x64 (rows wr*64+[0,64) in
// half0 AND 128+wr*64+[0,64) in half1 -> phase (mh,nh) touches only A-half mh,
// B-half nh). Per phase: 12 ds_read_b128 || 2 global_load_lds || 16 MFMA,
// barrier / MFMA / barrier; counted vmcnt(4) once per K-tile (never 0 in
// steady state). LDS 128KB: A [buf][h] @ 0, B [buf][h] @ 64K.
// Race-freedom: a phase's stage targets the region whose last ds_read was in
// the PREVIOUS phase (its end barrier follows everyone's lgkmcnt(0));
// vmcnt(4)@phase-4 retires all 4 half-tiles of the next K-tile.
// ---------------------------------------------------------------------------
__global__ __launch_bounds__(512, 2) void gemm_bt(
    const unsigned short* __restrict__ Xb, const unsigned short* __restrict__ Wb,
    const float* __restrict__ bias, float* __restrict__ out) {
  __shared__ __align__(16) char smem[131072];

  int bid = blockIdx.x;
  int swzb = (bid & 7) * (NWG / 8) + (bid >> 3);   // XCD-aware (688 % 8 == 0)
  int bm = swzb / NBN, bn = swzb % NBN;

  int tid = threadIdx.x, lane = tid & 63, w = tid >> 6;
  int wr = w >> 2, wc = w & 3;
  int lr = lane & 15, gk = lane >> 4;

  const char* aT = (const char*)Xb + (size_t)bm * (KT * 2 * 16384);
  const char* bT = (const char*)Wb + (size_t)bn * (KT * 2 * 16384);
  int w1024 = w << 10, lane16 = lane << 4;

  // Read-side swizzle folds to a per-lane constant: row&7 == lane&7.
  int X = (lane & 7) << 4;
  int koffs[2] = { ((gk << 4)) ^ X, (64 + (gk << 4)) ^ X };
  int arow[4], brow[2];
#pragma unroll
  for (int m = 0; m < 4; ++m) arow[m] = (wr * 64 + m * 16 + lr) * 128;
#pragma unroll
  for (int n = 0; n < 2; ++n) brow[n] = (wc * 32 + n * 16 + lr) * 128;

  auto stage = [&](int buf, int isB, int h, int kt_) {
    const char* s = (isB ? bT : aT) + ((size_t)kt_ * 2 + h) * 16384 + w1024 + lane16;
    char* d = smem + (isB ? 65536 : 0) + ((buf << 1) + h) * 16384 + w1024;
    load_lds16(s, d);
    load_lds16(s + 8192, d + 8192);
  };

  f32x4 acc[8][4] = {};

  // Prologue: tile0 fully + A0,B0 of tile1 (6 half-tiles = 12 loads);
  // vmcnt(4) retires tile0's 8, keeps tile1's A0,B0 in flight.
  stage(0, 0, 0, 0); stage(0, 0, 1, 0); stage(0, 1, 0, 0); stage(0, 1, 1, 0);
  stage(1, 0, 0, 1); stage(1, 1, 0, 1);
  asm volatile("s_waitcnt vmcnt(4)" ::: "memory");
  asm volatile("s_barrier" ::: "memory");

#define PHASE(CUR, MH, NH, ISSUE, ENDW) do {                                   \
    const char* Ab = smem + (((CUR) << 1) + (MH)) * 16384;                     \
    const char* Bb = smem + 65536 + (((CUR) << 1) + (NH)) * 16384;             \
    bf16x8 a_[4][2], b_[2][2];                                                 \
    _Pragma("unroll") for (int m_ = 0; m_ < 4; ++m_)                           \
      _Pragma("unroll") for (int ks_ = 0; ks_ < 2; ++ks_)                      \
        a_[m_][ks_] = *(const bf16x8*)(Ab + arow[m_] + koffs[ks_]);            \
    _Pragma("unroll") for (int n_ = 0; n_ < 2; ++n_)                           \
      _Pragma("unroll") for (int ks_ = 0; ks_ < 2; ++ks_)                      \
        b_[n_][ks_] = *(const bf16x8*)(Bb + brow[n_] + koffs[ks_]);            \
    ISSUE;                                                                     \
    asm volatile("s_barrier" ::: "memory");                                    \
    __builtin_amdgcn_s_setprio(1);                                             \
    _Pragma("unroll") for (int m_ = 0; m_ < 4; ++m_)                           \
      _Pragma("unroll") for (int n_ = 0; n_ < 2; ++n_)                         \
        _Pragma("unroll") for (int ks_ = 0; ks_ < 2; ++ks_)                    \
          acc[(MH) * 4 + m_][(NH) * 2 + n_] =                                  \
              __builtin_amdgcn_mfma_f32_16x16x32_bf16(                         \
                  a_[m_][ks_], b_[n_][ks_], acc[(MH) * 4 + m_][(NH) * 2 + n_], \
                  0, 0, 0);                                                    \
    __builtin_amdgcn_s_setprio(0);                                             \
    ENDW;                                                                      \
    asm volatile("s_barrier" ::: "memory");                                    \
  } while (0)

#pragma unroll 2
  for (int t = 0; t < KT; ++t) {
    int cur = t & 1, nxt = cur ^ 1;
    // phase 1: reads A[cur][0], B[cur][0]; stage A-half1 of tile t+1 (dead since t-1 p4)
    PHASE(cur, 0, 0, { if (t + 1 < KT) stage(nxt, 0, 1, t + 1); }, {});
    // phase 2: reads A[cur][0], B[cur][1]; stage B-half1 of tile t+1
    PHASE(cur, 0, 1, { if (t + 1 < KT) stage(nxt, 1, 1, t + 1); }, {});
    // phase 3: reads A[cur][1], B[cur][0]; stage A-half0 of tile t+2 (A[cur][0] died at p2)
    PHASE(cur, 1, 0, { if (t + 2 < KT) stage(cur, 0, 0, t + 2); }, {});
    // phase 4: reads A[cur][1], B[cur][1]; stage B-half0 of tile t+2; counted vmcnt
    PHASE(cur, 1, 1, { if (t + 2 < KT) stage(cur, 1, 0, t + 2); },
          { if (t >= KT - 2) { asm volatile("s_waitcnt vmcnt(0)" ::: "memory"); }
            else             { asm volatile("s_waitcnt vmcnt(4)" ::: "memory"); } });
  }
#undef PHASE

  // Epilogue. C/D layout: col=lane&15, row=(lane>>4)*4+reg [m89-verified].
  float bv[2][2];
#pragma unroll
  for (int nh = 0; nh < 2; ++nh)
#pragma unroll
    for (int n = 0; n < 2; ++n)
      bv[nh][n] = bias[bn * 256 + nh * 128 + wc * 32 + n * 16 + lr];

  int colb = bn * 256 + wc * 32 + lr;
#pragma unroll
  for (int mh = 0; mh < 2; ++mh)
#pragma unroll
    for (int m = 0; m < 4; ++m)
#pragma unroll
      for (int r = 0; r < 4; ++r) {
        int row = bm * 256 + mh * 128 + wr * 64 + m * 16 + (gk << 2) + r;
        float* po = out + (size_t)row * OUT_F + colb;
#pragma unroll
        for (int nh = 0; nh < 2; ++nh)
#pragma unroll
          for (int n = 0; n < 2; ++n)
            po[nh * 128 + n * 16] = acc[mh * 4 + m][nh * 2 + n][r] + bv[nh][n];
      }
}

// ---------------------------------------------------------------------------
extern "C" void kernel_launch(void* const* d_in, const int* in_sizes, int n_in,
                              void* d_out, int out_size, void* d_ws, size_t ws_size,
                              hipStream_t stream) {
  const float* x    = (const float*)d_in[0];
  const int*   wq   = (const int*)d_in[1];
  const float* wn   = (const float*)d_in[2];   // fp16 widened to f32 by harness
  const float* bias = (const float*)d_in[3];
  float*       out  = (float*)d_out;

  // Workspace: Xb (32 MB) then Wb (~86 MB), bf16 tile-linear pre-swizzled.
  unsigned short* Xb = (unsigned short*)d_ws;
  unsigned short* Wb = Xb + (size_t)TOKENS * IN_F;

  conv_x<<<(TOKENS * IN_F / 8) / 256, 256, 0, stream>>>(x, Xb);
  dequant_w<<<TOTAL_GROUPS / 256, 256, 0, stream>>>(wq, wn, Wb);
  gemm_bt<<<NWG, 512, 0, stream>>>(Xb, Wb, bias, out);
}